// Round 16
// baseline (496.700 us; speedup 1.0000x reference)
//
#include <hip/hip_runtime.h>
#include <hip/hip_bf16.h>

#define NN 50000
#define EE 800000
#define HIDD 128
#define NL 4
#define NC 10
#define BN_EPS 1e-5f
#define NCHUNK 782   // ceil(NN/64)

typedef __bf16 bf16x8 __attribute__((ext_vector_type(8)));
typedef float f32x4 __attribute__((ext_vector_type(4)));

__device__ __forceinline__ float bf_lo(unsigned int u) { return __uint_as_float(u << 16); }
__device__ __forceinline__ float bf_hi(unsigned int u) { return __uint_as_float(u & 0xFFFF0000u); }

// ---------------- runtime dtype detection ----------------
// flags[0]: 1 = float inputs are fp32, 0 = bf16
// flags[1]: 1 = edge_index is int64, 0 = int32
__global__ void k_detect(const void* h, const void* ei, int* flags) {
    __shared__ int wild, zeros;
    if (threadIdx.x == 0) { wild = 0; zeros = 0; }
    __syncthreads();
    int t = threadIdx.x;
    const unsigned short* hb = (const unsigned short*)h;
    int lw = 0;
    for (int i = t; i < 4096; i += 256) {
        unsigned short u = hb[i];
        int e = (u >> 7) & 0xFF;
        if ((e >= 0x8F || e == 0) && (u & 0x7FFF) != 0) lw++;
    }
    atomicAdd(&wild, lw);
    const int* ii = (const int*)ei;
    int lz = 0;
    for (int i = t; i < 512; i += 256)
        if (ii[2 * i + 1] == 0) lz++;
    atomicAdd(&zeros, lz);
    __syncthreads();
    if (threadIdx.x == 0) {
        flags[0] = (wild > 256) ? 1 : 0;
        flags[1] = (zeros > 256) ? 1 : 0;
    }
}

__device__ __forceinline__ int edge_at(const void* ei, int i64, long long idx) {
    return i64 ? (int)((const long long*)ei)[idx] : ((const int*)ei)[idx];
}

__device__ __forceinline__ float flt_at(const void* p, int fp32, size_t idx) {
    return fp32 ? ((const float*)p)[idx] : (float)((const __hip_bfloat16*)p)[idx];
}

// edge_index -> int32 src/dst arrays (single streaming pass)
__global__ void k_cvt_edges(const void* ei, int* src32, int* dst32, const int* flags) {
    int e = blockIdx.x * 256 + threadIdx.x;
    if (e >= EE) return;
    int i64 = flags[1];
    src32[e] = edge_at(ei, i64, e);
    dst32[e] = edge_at(ei, i64, (long long)EE + e);
}

// convert the 6 small float arrays + zero counts in one launch (12 blocks)
__global__ void k_cvt_small(const void* bemb, const void* bs, const void* gam,
                            const void* bet, const void* Wm, const void* bm,
                            float* bemb_f, float* bs_f, float* gam_f, float* bet_f,
                            float* Wm_f, float* bm_f, int* counts, const int* flags) {
    int i = blockIdx.x * 256 + threadIdx.x;
    for (int j = i; j < 12500; j += 3072)
        ((int4*)counts)[j] = make_int4(0, 0, 0, 0);
    int fp32 = flags[0];
    const void* src; float* dst; int off;
    if (i < 128)       { src = bemb; dst = bemb_f; off = i; }
    else if (i < 640)  { src = bs;   dst = bs_f;   off = i - 128; }
    else if (i < 1152) { src = gam;  dst = gam_f;  off = i - 640; }
    else if (i < 1664) { src = bet;  dst = bet_f;  off = i - 1152; }
    else if (i < 2944) { src = Wm;   dst = Wm_f;   off = i - 1664; }
    else if (i < 2954) { src = bm;   dst = bm_f;   off = i - 2944; }
    else return;
    dst[off] = flt_at(src, fp32, off);
}

// ---------------- graph preprocessing ----------------
// XCD-range swizzle: block's dst-range = blockIdx&7 (matches round-robin XCD dispatch).

__global__ void k_count_edges(const int* __restrict__ dst32, int* counts) {
    int rlo = (blockIdx.x & 7) * 6250, rhi = rlo + 6250;
    for (int c = (int)(blockIdx.x >> 3); c < 3125; c += 391) {
        int e = c * 256 + threadIdx.x;
        if (e < EE) {
            int d = dst32[e];
            if (d >= rlo && d < rhi) atomicAdd(&counts[d], 1);
        }
    }
}

// exclusive scan of (counts+1) -> offsets
__global__ void k_scan1(const int* counts, int* offsets, int* bsums) {
    __shared__ int sc[256];
    int tid = threadIdx.x;
    int base = blockIdx.x * 1024 + tid * 4;
    int4 c = {0, 0, 0, 0};
    int4 d = {0, 0, 0, 0};
    if (base + 3 < NN) {
        c = *(const int4*)(counts + base);
        d.x = c.x + 1; d.y = c.y + 1; d.z = c.z + 1; d.w = c.w + 1;
    } else {
        if (base + 0 < NN) d.x = counts[base] + 1;
        if (base + 1 < NN) d.y = counts[base + 1] + 1;
        if (base + 2 < NN) d.z = counts[base + 2] + 1;
        if (base + 3 < NN) d.w = counts[base + 3] + 1;
    }
    int s = d.x + d.y + d.z + d.w;
    sc[tid] = s;
    __syncthreads();
    for (int off = 1; off < 256; off <<= 1) {
        int v = (tid >= off) ? sc[tid - off] : 0;
        __syncthreads();
        sc[tid] += v;
        __syncthreads();
    }
    int excl = sc[tid] - s;
    if (base < NN) {
        int4 o;
        o.x = excl; o.y = excl + d.x; o.z = o.y + d.y; o.w = o.z + d.z;
        *(int4*)(offsets + base) = o;
    }
    if (tid == 255) bsums[blockIdx.x] = sc[255];
}

// finalize offsets (each block redundantly scans the 49 block-sums in LDS)
// + zero cursor + compute dinv + place self-loops
__global__ void k_scan3(int* offsets, const int* bsums, const int* counts,
                        int* cursor, float* dinv, int* csr, int nb) {
    __shared__ int sc[64];
    int tid = threadIdx.x;
    if (tid < 64) {
        int v = (tid < nb) ? bsums[tid] : 0;
        sc[tid] = v;
    }
    __syncthreads();
    // inclusive scan over 64 entries (single wave of the first 64 threads would
    // race with barriers; do it serially in thread 0 — 49 adds, trivial)
    if (tid == 0) {
        int run = 0;
        for (int i = 0; i < nb; ++i) { int t = sc[i]; sc[i] = run; run += t; }
    }
    __syncthreads();
    int add = sc[blockIdx.x];
    int base = blockIdx.x * 1024 + tid * 4;
    if (base >= NN) return;
    int4 o = *(int4*)(offsets + base);
    o.x += add; o.y += add; o.z += add; o.w += add;
    *(int4*)(offsets + base) = o;
    int ov[4] = {o.x, o.y, o.z, o.w};
#pragma unroll
    for (int t = 0; t < 4; ++t) {
        int i = base + t;
        if (i < NN) {
            int c = counts[i];
            cursor[i] = 0;
            dinv[i] = rsqrtf((float)(c + 1));
            csr[ov[t] + c] = i;  // self-loop in last slot of segment
        }
    }
}

__global__ void k_fill_edges(const int* __restrict__ src32, const int* __restrict__ dst32,
                             const int* offsets, int* cursor, int* csr) {
    int rlo = (blockIdx.x & 7) * 6250, rhi = rlo + 6250;
    for (int c = (int)(blockIdx.x >> 3); c < 3125; c += 391) {
        int e = c * 256 + threadIdx.x;
        if (e < EE) {
            int d = dst32[e];
            if (d >= rlo && d < rhi) {
                int s = src32[e];
                if ((unsigned)s < NN) {
                    int pos = offsets[d] + atomicAdd(&cursor[d], 1);
                    csr[pos] = s;
                }
            }
        }
    }
}

// ---------------- weight packing into MFMA B-fragment order (hi/lo planes) ----------------
__global__ void k_pack(const void* Wemb, const void* Ws, __bf16* Bhi, __bf16* Blo,
                       const int* flags) {
    int idx = blockIdx.x * 256 + threadIdx.x;
    if (idx >= 5 * 16384) return;
    int m = idx >> 14, r = idx & 16383;
    int kt = r >> 12, nt = (r >> 9) & 7, lane = (r >> 3) & 63, j = r & 7;
    int k = kt * 32 + (lane >> 4) * 8 + j;
    int n = nt * 16 + (lane & 15);
    int fp32 = flags[0];
    float w;
    if (m == 0) w = flt_at(Wemb, fp32, (size_t)k * 128 + n);
    else        w = flt_at(Ws, fp32, (size_t)(m - 1) * 16384 + (size_t)k * 128 + n);
    __bf16 hi = (__bf16)w;
    Bhi[idx] = hi;
    Blo[idx] = (__bf16)(w - (float)hi);
}

// ---------------- BN affine helper: S,T from raw sums ----------------
__device__ __forceinline__ void bn_affine(float sm, float sq, float g, float be,
                                          float& S, float& T) {
    float mu = sm * (1.f / NN);
    float var = fmaxf(sq * (1.f / NN) - mu * mu, 0.f);
    S = rsqrtf(var + BN_EPS) * g;
    T = be - mu * S;
}

// sum 8 replicas of column-quad cb from stats8
__device__ __forceinline__ void sum_reps(const float* ST, int cb, float4& sm, float4& sq) {
    sm = make_float4(0.f, 0.f, 0.f, 0.f);
    sq = make_float4(0.f, 0.f, 0.f, 0.f);
#pragma unroll
    for (int rr = 0; rr < 8; ++rr) {
        float4 a = *(const float4*)(ST + rr * 256 + cb);
        float4 b = *(const float4*)(ST + rr * 256 + 128 + cb);
        sm.x += a.x; sm.y += a.y; sm.z += a.z; sm.w += a.w;
        sq.x += b.x; sq.y += b.y; sq.z += b.z; sq.w += b.w;
    }
}

// ---------------- MFMA GEMM ----------------
// mode 0: A = raw network input (fp32/bf16 per flags[0]); bias in epilogue; fp32 C out.
// mode 1: A = fp32 hbuf; bf16 Cb out (row layout xb[node][64 uint]).
// mode 2: A-row = hbuf + relu(abuf*S + T); writes h' to Hout; bf16 Cb out.
__global__ __launch_bounds__(256) void k_gemm_mfma(const void* __restrict__ Araw,
                                                   const float* __restrict__ Aagg,
                                                   const float* __restrict__ ST,
                                                   const float* __restrict__ gamma,
                                                   const float* __restrict__ beta,
                                                   const __bf16* __restrict__ Bhi,
                                                   const __bf16* __restrict__ Blo,
                                                   const float* __restrict__ bias,
                                                   float* __restrict__ C,
                                                   unsigned short* __restrict__ Cb,
                                                   float* __restrict__ Hout,
                                                   int M, int mode, const int* flags) {
    // a_hi/a_lo overlaid with the epilogue C-scratch (dead after MFMA loop)
    __shared__ __align__(16) char smem[2 * 64 * 136 * 2];  // 34816 B
    __bf16 (*a_hi)[136] = (__bf16(*)[136])smem;
    __bf16 (*a_lo)[136] = (__bf16(*)[136])(smem + 64 * 136 * 2);
    float (*Cs)[132] = (float(*)[132])smem;                 // 33792 B, fits
    int tid = threadIdx.x;
    int r0 = blockIdx.x * 64;
    int cq = tid & 31;
    int rb = tid >> 5;
    int cb = cq * 4;
    float4 S4, T4;
    if (mode == 2) {
        float4 sm, sq;
        sum_reps(ST, cb, sm, sq);
        float4 g  = *(const float4*)(gamma + cb);
        float4 be = *(const float4*)(beta + cb);
        bn_affine(sm.x, sq.x, g.x, be.x, S4.x, T4.x);
        bn_affine(sm.y, sq.y, g.y, be.y, S4.y, T4.y);
        bn_affine(sm.z, sq.z, g.z, be.z, S4.z, T4.z);
        bn_affine(sm.w, sq.w, g.w, be.w, S4.w, T4.w);
    }
    int afp32 = (mode == 0) ? flags[0] : 1;
#pragma unroll
    for (int p = 0; p < 8; ++p) {
        int r = rb + p * 8;
        int gr = r0 + r;
        float f[4] = {0.f, 0.f, 0.f, 0.f};
        if (gr < M) {
            if (mode == 0) {
                if (afp32) {
                    float4 v = ((const float4*)Araw)[(size_t)gr * 32 + cq];
                    f[0] = v.x; f[1] = v.y; f[2] = v.z; f[3] = v.w;
                } else {
                    const __hip_bfloat16* ab = (const __hip_bfloat16*)Araw + (size_t)gr * 128 + cb;
#pragma unroll
                    for (int t = 0; t < 4; ++t) f[t] = (float)ab[t];
                }
            } else {
                float4 v = *(const float4*)((const float*)Araw + (size_t)gr * 128 + cb);
                if (mode == 2) {
                    float4 a = *(const float4*)(Aagg + (size_t)gr * 128 + cb);
                    v.x += fmaxf(fmaf(a.x, S4.x, T4.x), 0.f);
                    v.y += fmaxf(fmaf(a.y, S4.y, T4.y), 0.f);
                    v.z += fmaxf(fmaf(a.z, S4.z, T4.z), 0.f);
                    v.w += fmaxf(fmaf(a.w, S4.w, T4.w), 0.f);
                    *(float4*)(Hout + (size_t)gr * 128 + cb) = v;
                }
                f[0] = v.x; f[1] = v.y; f[2] = v.z; f[3] = v.w;
            }
        }
        union { __bf16 b[4]; ushort4 u; } ph, pl;
#pragma unroll
        for (int t = 0; t < 4; ++t) {
            __bf16 hi = (__bf16)f[t];
            ph.b[t] = hi;
            pl.b[t] = (__bf16)(f[t] - (float)hi);
        }
        *(ushort4*)&a_hi[r][cb] = ph.u;
        *(ushort4*)&a_lo[r][cb] = pl.u;
    }
    __syncthreads();
    int lane = tid & 63, wave = tid >> 6;
    int quad = lane >> 4, l15 = lane & 15;
    int rw = wave * 16;
    f32x4 acc[8];
#pragma unroll
    for (int nt = 0; nt < 8; ++nt) acc[nt] = (f32x4){0.f, 0.f, 0.f, 0.f};
#pragma unroll
    for (int kt = 0; kt < 4; ++kt) {
        int k0 = kt * 32 + quad * 8;
        bf16x8 ah = *(const bf16x8*)&a_hi[rw + l15][k0];
        bf16x8 al = *(const bf16x8*)&a_lo[rw + l15][k0];
#pragma unroll
        for (int nt = 0; nt < 8; ++nt) {
            size_t boff = (((size_t)(kt * 8 + nt) * 64 + lane) * 8);
            bf16x8 bh = *(const bf16x8*)(Bhi + boff);
            bf16x8 bl = *(const bf16x8*)(Blo + boff);
            acc[nt] = __builtin_amdgcn_mfma_f32_16x16x32_bf16(ah, bh, acc[nt], 0, 0, 0);
            acc[nt] = __builtin_amdgcn_mfma_f32_16x16x32_bf16(al, bh, acc[nt], 0, 0, 0);
            acc[nt] = __builtin_amdgcn_mfma_f32_16x16x32_bf16(ah, bl, acc[nt], 0, 0, 0);
        }
    }
    // epilogue: stage C tile in LDS, then coalesced wide stores
    __syncthreads();
#pragma unroll
    for (int nt = 0; nt < 8; ++nt) {
        int col = nt * 16 + l15;
#pragma unroll
        for (int reg = 0; reg < 4; ++reg)
            Cs[rw + quad * 4 + reg][col] = acc[nt][reg];
    }
    __syncthreads();
#pragma unroll
    for (int p = 0; p < 4; ++p) {
        int row = (tid >> 4) + p * 16;
        int gr = r0 + row;
        if (gr >= M) continue;
        int colc = (tid & 15) * 8;
        float v[8];
        *(float4*)&v[0] = *(const float4*)&Cs[row][colc];
        *(float4*)&v[4] = *(const float4*)&Cs[row][colc + 4];
        if (bias) {
            float4 b0 = *(const float4*)(bias + colc);
            float4 b1 = *(const float4*)(bias + colc + 4);
            v[0] += b0.x; v[1] += b0.y; v[2] += b0.z; v[3] += b0.w;
            v[4] += b1.x; v[5] += b1.y; v[6] += b1.z; v[7] += b1.w;
        }
        if (Cb) {
            union { unsigned short us[8]; uint4 u4; } pk;
#pragma unroll
            for (int t = 0; t < 8; ++t)
                pk.us[t] = __bfloat16_as_ushort(__float2bfloat16(v[t]));
            *(uint4*)(Cb + (size_t)gr * 128 + colc) = pk.u4;
        } else {
            float* cr = C + (size_t)gr * 128 + colc;
            *(float4*)cr = *(float4*)&v[0];
            *(float4*)(cr + 4) = *(float4*)&v[4];
        }
    }
}

// ---------------- aggregation + stats8 zeroing ----------------
// Row layout xb[node][64 uint]. 16B/lane gather: lane quarter q handles edge j+q;
// one load inst covers 4 edges; 2 loads in flight; single-load tail for <=4 edges.
__global__ __launch_bounds__(256) void k_agg(const unsigned int* __restrict__ xb,
                                             const int* __restrict__ csr,
                                             const int* __restrict__ offsets,
                                             const int* __restrict__ counts,
                                             const float* __restrict__ dinv,
                                             const float* __restrict__ bias,
                                             float* __restrict__ out,
                                             float* __restrict__ stats8) {
    if (blockIdx.x < 8) stats8[blockIdx.x * 256 + threadIdx.x] = 0.f;  // zero replicas
    int node = blockIdx.x * 4 + (threadIdx.x >> 6);
    int lane = threadIdx.x & 63;
    int l15 = lane & 15;
    int quarter = lane >> 4;
    int start = offsets[node];
    int cnt = counts[node] + 1;  // + self-loop
    float dn = dinv[node];
    float accA[8] = {0.f, 0.f, 0.f, 0.f, 0.f, 0.f, 0.f, 0.f};
    float accB[8] = {0.f, 0.f, 0.f, 0.f, 0.f, 0.f, 0.f, 0.f};
    for (int base = 0; base < cnt; base += 64) {
        int sidx = 0;
        float wl = 0.f;
        if (base + lane < cnt) {
            sidx = csr[start + base + lane];
            wl = dinv[sidx] * dn;  // wl = 0 for slots beyond cnt
        }
        int m = min(64, cnt - base);
        int j = 0;
        for (; j + 4 < m; j += 8) {        // >=5 edges remain: 2 loads (8 edges)
            int e0 = j + quarter;
            int e1 = j + 4 + quarter;
            int s0 = __shfl(sidx, e0);
            float w0 = __shfl(wl, e0);
            int s1 = __shfl(sidx, e1);
            float w1 = __shfl(wl, e1);
            uint4 u0 = *((const uint4*)(xb + (size_t)s0 * 64) + l15);
            uint4 u1 = *((const uint4*)(xb + (size_t)s1 * 64) + l15);
            accA[0] = fmaf(bf_lo(u0.x), w0, accA[0]);
            accA[1] = fmaf(bf_hi(u0.x), w0, accA[1]);
            accA[2] = fmaf(bf_lo(u0.y), w0, accA[2]);
            accA[3] = fmaf(bf_hi(u0.y), w0, accA[3]);
            accA[4] = fmaf(bf_lo(u0.z), w0, accA[4]);
            accA[5] = fmaf(bf_hi(u0.z), w0, accA[5]);
            accA[6] = fmaf(bf_lo(u0.w), w0, accA[6]);
            accA[7] = fmaf(bf_hi(u0.w), w0, accA[7]);
            accB[0] = fmaf(bf_lo(u1.x), w1, accB[0]);
            accB[1] = fmaf(bf_hi(u1.x), w1, accB[1]);
            accB[2] = fmaf(bf_lo(u1.y), w1, accB[2]);
            accB[3] = fmaf(bf_hi(u1.y), w1, accB[3]);
            accB[4] = fmaf(bf_lo(u1.z), w1, accB[4]);
            accB[5] = fmaf(bf_hi(u1.z), w1, accB[5]);
            accB[6] = fmaf(bf_lo(u1.w), w1, accB[6]);
            accB[7] = fmaf(bf_hi(u1.w), w1, accB[7]);
        }
        if (j < m) {                        // <=4 edges remain: 1 load
            int e0 = j + quarter;
            int s0 = __shfl(sidx, e0);
            float w0 = __shfl(wl, e0);
            uint4 u0 = *((const uint4*)(xb + (size_t)s0 * 64) + l15);
            accA[0] = fmaf(bf_lo(u0.x), w0, accA[0]);
            accA[1] = fmaf(bf_hi(u0.x), w0, accA[1]);
            accA[2] = fmaf(bf_lo(u0.y), w0, accA[2]);
            accA[3] = fmaf(bf_hi(u0.y), w0, accA[3]);
            accA[4] = fmaf(bf_lo(u0.z), w0, accA[4]);
            accA[5] = fmaf(bf_hi(u0.z), w0, accA[5]);
            accA[6] = fmaf(bf_lo(u0.w), w0, accA[6]);
            accA[7] = fmaf(bf_hi(u0.w), w0, accA[7]);
        }
    }
#pragma unroll
    for (int k = 0; k < 8; ++k) {
        float a = accA[k] + accB[k];
        a += __shfl_xor(a, 16);
        a += __shfl_xor(a, 32);
        accA[k] = a;
    }
    if (quarter == 0) {
        int col = l15 * 8;
        float4 o0, o1;
        o0.x = accA[0] + bias[col + 0];
        o0.y = accA[1] + bias[col + 1];
        o0.z = accA[2] + bias[col + 2];
        o0.w = accA[3] + bias[col + 3];
        o1.x = accA[4] + bias[col + 4];
        o1.y = accA[5] + bias[col + 5];
        o1.z = accA[6] + bias[col + 6];
        o1.w = accA[7] + bias[col + 7];
        float* orow = out + (size_t)node * 128 + col;
        *(float4*)orow = o0;
        *(float4*)(orow + 4) = o1;
    }
}

// ---------------- batchnorm partials: grid-stride, 8-replica atomics ----------------
__global__ __launch_bounds__(256) void k_bnred(const float* __restrict__ agg,
                                               float* __restrict__ stats8) {
    int tid = threadIdx.x;
    int rt = tid >> 5, cq = tid & 31;   // 8 row-threads x 32 col-quads
    float4 s = {0.f, 0.f, 0.f, 0.f}, ss = {0.f, 0.f, 0.f, 0.f};
    for (int chunk = blockIdx.x; chunk < NCHUNK; chunk += gridDim.x) {
        int r0 = chunk * 64;
#pragma unroll
        for (int p = 0; p < 8; ++p) {
            int row = r0 + p * 8 + rt;
            if (row < NN) {
                float4 v = *(const float4*)(agg + (size_t)row * 128 + cq * 4);
                s.x += v.x; s.y += v.y; s.z += v.z; s.w += v.w;
                ss.x = fmaf(v.x, v.x, ss.x);
                ss.y = fmaf(v.y, v.y, ss.y);
                ss.z = fmaf(v.z, v.z, ss.z);
                ss.w = fmaf(v.w, v.w, ss.w);
            }
        }
    }
    __shared__ float4 lsum[8][33], lssq[8][33];
    lsum[rt][cq] = s;
    lssq[rt][cq] = ss;
    __syncthreads();
    if (tid < 32) {
        float4 ts = lsum[0][tid], tq = lssq[0][tid];
#pragma unroll
        for (int r = 1; r < 8; ++r) {
            float4 a = lsum[r][tid], b = lssq[r][tid];
            ts.x += a.x; ts.y += a.y; ts.z += a.z; ts.w += a.w;
            tq.x += b.x; tq.y += b.y; tq.z += b.z; tq.w += b.w;
        }
        float* st = stats8 + (blockIdx.x & 7) * 256;
        atomicAdd(&st[tid * 4 + 0], ts.x);
        atomicAdd(&st[tid * 4 + 1], ts.y);
        atomicAdd(&st[tid * 4 + 2], ts.z);
        atomicAdd(&st[tid * 4 + 3], ts.w);
        atomicAdd(&st[128 + tid * 4 + 0], tq.x);
        atomicAdd(&st[128 + tid * 4 + 1], tq.y);
        atomicAdd(&st[128 + tid * 4 + 2], tq.z);
        atomicAdd(&st[128 + tid * 4 + 3], tq.w);
    }
}

// ---------------- fused final BN + MLP: out[N x 10] ----------------
__global__ __launch_bounds__(256) void k_mlp_fused(const float* __restrict__ h,
                                                   const float* __restrict__ agg,
                                                   const float* __restrict__ ST,
                                                   const float* __restrict__ gamma,
                                                   const float* __restrict__ beta,
                                                   const float* __restrict__ Wm,
                                                   const float* __restrict__ bm,
                                                   void* __restrict__ out,
                                                   const int* __restrict__ flags) {
    __shared__ float Wt[10][132];
    int tid = threadIdx.x;
    for (int i = tid; i < 1280; i += 256) {
        int cls = i >> 7, k = i & 127;
        Wt[cls][k] = Wm[k * 10 + cls];
    }
    __syncthreads();
    int wave = tid >> 6, lane = tid & 63;
    int nl = lane >> 4, c = lane & 15;
    int node = blockIdx.x * 16 + wave * 4 + nl;
    size_t rowo = (size_t)node * 128 + c * 8;
    float4 h0 = *(const float4*)(h + rowo);
    float4 h1 = *(const float4*)(h + rowo + 4);
    float4 a0 = *(const float4*)(agg + rowo);
    float4 a1 = *(const float4*)(agg + rowo + 4);
    float S[8], T[8];
#pragma unroll
    for (int q = 0; q < 2; ++q) {
        float4 sm, sq;
        sum_reps(ST, c * 8 + q * 4, sm, sq);
        float4 g  = *(const float4*)(gamma + c * 8 + q * 4);
        float4 be = *(const float4*)(beta + c * 8 + q * 4);
        bn_affine(sm.x, sq.x, g.x, be.x, S[q * 4 + 0], T[q * 4 + 0]);
        bn_affine(sm.y, sq.y, g.y, be.y, S[q * 4 + 1], T[q * 4 + 1]);
        bn_affine(sm.z, sq.z, g.z, be.z, S[q * 4 + 2], T[q * 4 + 2]);
        bn_affine(sm.w, sq.w, g.w, be.w, S[q * 4 + 3], T[q * 4 + 3]);
    }
    float hv[8];
    hv[0] = h0.x + fmaxf(fmaf(a0.x, S[0], T[0]), 0.f);
    hv[1] = h0.y + fmaxf(fmaf(a0.y, S[1], T[1]), 0.f);
    hv[2] = h0.z + fmaxf(fmaf(a0.z, S[2], T[2]), 0.f);
    hv[3] = h0.w + fmaxf(fmaf(a0.w, S[3], T[3]), 0.f);
    hv[4] = h1.x + fmaxf(fmaf(a1.x, S[4], T[4]), 0.f);
    hv[5] = h1.y + fmaxf(fmaf(a1.y, S[5], T[5]), 0.f);
    hv[6] = h1.z + fmaxf(fmaf(a1.z, S[6], T[6]), 0.f);
    hv[7] = h1.w + fmaxf(fmaf(a1.w, S[7], T[7]), 0.f);
    float p[10];
#pragma unroll
    for (int cls = 0; cls < 10; ++cls) {
        float4 w0 = *(const float4*)&Wt[cls][c * 8];
        float4 w1 = *(const float4*)&Wt[cls][c * 8 + 4];
        float sacc = fmaf(hv[0], w0.x, fmaf(hv[1], w0.y, fmaf(hv[2], w0.z, hv[3] * w0.w)));
        sacc = fmaf(hv[4], w1.x, fmaf(hv[5], w1.y, fmaf(hv[6], w1.z, fmaf(hv[7], w1.w, sacc))));
        p[cls] = sacc;
    }
#pragma unroll
    for (int m = 1; m < 16; m <<= 1)
#pragma unroll
        for (int cls = 0; cls < 10; ++cls)
            p[cls] += __shfl_xor(p[cls], m);
    if (c == 0) {
        if (flags[0]) {
            float* o = (float*)out;
            for (int cls = 0; cls < 10; ++cls) o[node * 10 + cls] = p[cls] + bm[cls];
        } else {
            __hip_bfloat16* o = (__hip_bfloat16*)out;
            for (int cls = 0; cls < 10; ++cls)
                o[node * 10 + cls] = __float2bfloat16(p[cls] + bm[cls]);
        }
    }
}

// ---------------- orchestration ----------------

extern "C" void kernel_launch(void* const* d_in, const int* in_sizes, int n_in,
                              void* d_out, int out_size, void* d_ws, size_t ws_size,
                              hipStream_t stream) {
    const void* h_in = d_in[0];
    const void* ei   = d_in[1];
    const void* Wemb = d_in[3];
    const void* bemb = d_in[4];
    const void* Ws   = d_in[5];
    const void* bs   = d_in[6];
    const void* gam  = d_in[7];
    const void* bet  = d_in[8];
    const void* Wm   = d_in[9];
    const void* bm   = d_in[10];

    char* ws = (char*)d_ws;
    size_t off = 0;
    auto alloc = [&](size_t bytes) -> void* {
        void* p = ws + off;
        off = (off + bytes + 255) & ~(size_t)255;
        return p;
    };
    float* hbuf    = (float*)alloc((size_t)NN * 128 * 4);
    float* abuf    = (float*)alloc((size_t)NN * 128 * 4);
    unsigned int* xb = (unsigned int*)alloc((size_t)NN * 64 * 4);   // bf16 x, 256 B/row
    int* counts    = (int*)alloc((size_t)(NN + 1024) * 4);
    int* offsets   = (int*)alloc((size_t)(NN + 1024) * 4);
    int* cursor    = (int*)alloc((size_t)NN * 4);
    int* bsums     = (int*)alloc(64 * 4);
    float* dinv    = (float*)alloc((size_t)NN * 4);
    float* stats8  = (float*)alloc((size_t)8 * 256 * 4);
    int* csr       = (int*)alloc((size_t)(EE + NN + 64) * 4);
    int* src32     = (int*)alloc((size_t)EE * 4);
    int* dst32     = (int*)alloc((size_t)EE * 4);
    int* flags     = (int*)alloc(64);
    float* bemb_f  = (float*)alloc(128 * 4);
    float* bs_f    = (float*)alloc(512 * 4);
    float* gam_f   = (float*)alloc(512 * 4);
    float* bet_f   = (float*)alloc(512 * 4);
    float* Wm_f    = (float*)alloc(1280 * 4);
    float* bm_f    = (float*)alloc(16 * 4);
    __bf16* Bhi    = (__bf16*)alloc((size_t)5 * 16384 * 2);
    __bf16* Blo    = (__bf16*)alloc((size_t)5 * 16384 * 2);

    k_detect<<<1, 256, 0, stream>>>(h_in, ei, flags);
    k_cvt_edges<<<(EE + 255) / 256, 256, 0, stream>>>(ei, src32, dst32, flags);
    k_cvt_small<<<12, 256, 0, stream>>>(bemb, bs, gam, bet, Wm, bm,
                                        bemb_f, bs_f, gam_f, bet_f, Wm_f, bm_f,
                                        counts, flags);
    k_pack<<<(5 * 16384 + 255) / 256, 256, 0, stream>>>(Wemb, Ws, Bhi, Blo, flags);

    k_count_edges<<<3128, 256, 0, stream>>>(dst32, counts);
    int nb = (NN + 1023) / 1024;  // 49
    k_scan1<<<nb, 256, 0, stream>>>(counts, offsets, bsums);
    k_scan3<<<nb, 256, 0, stream>>>(offsets, bsums, counts, cursor, dinv, csr, nb);
    k_fill_edges<<<3128, 256, 0, stream>>>(src32, dst32, offsets, cursor, csr);

    int gblocks = (NN + 63) / 64;  // 782
    // embedding: hbuf = input @ W_emb + b_emb  (fp32 out, raw input staged directly)
    k_gemm_mfma<<<gblocks, 256, 0, stream>>>(h_in, nullptr, nullptr, nullptr, nullptr,
                                             Bhi, Blo, bemb_f, hbuf, nullptr, nullptr,
                                             NN, 0, flags);

    for (int l = 0; l < NL; ++l) {
        if (l == 0) {
            k_gemm_mfma<<<gblocks, 256, 0, stream>>>(hbuf, nullptr, nullptr, nullptr, nullptr,
                                                     Bhi + (size_t)1 * 16384, Blo + (size_t)1 * 16384,
                                                     nullptr, nullptr, (unsigned short*)xb,
                                                     nullptr, NN, 1, flags);
        } else {
            // fused: h = h + relu(BN_{l-1}(abuf)), then x = h @ W_l
            k_gemm_mfma<<<gblocks, 256, 0, stream>>>(hbuf, abuf, stats8,
                                                     gam_f + (l - 1) * 128, bet_f + (l - 1) * 128,
                                                     Bhi + (size_t)(1 + l) * 16384,
                                                     Blo + (size_t)(1 + l) * 16384,
                                                     nullptr, nullptr, (unsigned short*)xb,
                                                     hbuf, NN, 2, flags);
        }
        k_agg<<<NN / 4, 256, 0, stream>>>(xb, csr, offsets, counts, dinv,
                                          bs_f + l * 128, abuf, stats8);
        k_bnred<<<196, 256, 0, stream>>>(abuf, stats8);
    }
    // final: h4 = h3 + relu(BN_3(abuf)); out = h4 @ W_mlp + b_mlp
    k_mlp_fused<<<NN / 16, 256, 0, stream>>>(hbuf, abuf, stats8,
                                             gam_f + 3 * 128, bet_f + 3 * 128,
                                             Wm_f, bm_f, d_out, flags);
}

// Round 17
// 490.427 us; speedup vs baseline: 1.0128x; 1.0128x over previous
//
#include <hip/hip_runtime.h>
#include <hip/hip_bf16.h>

#define NN 50000
#define EE 800000
#define HIDD 128
#define NL 4
#define NC 10
#define BN_EPS 1e-5f
#define NCHUNK 782   // ceil(NN/64)

typedef __bf16 bf16x8 __attribute__((ext_vector_type(8)));
typedef float f32x4 __attribute__((ext_vector_type(4)));

__device__ __forceinline__ float bf_lo(unsigned int u) { return __uint_as_float(u << 16); }
__device__ __forceinline__ float bf_hi(unsigned int u) { return __uint_as_float(u & 0xFFFF0000u); }

// ---------------- runtime dtype detection ----------------
// flags[0]: 1 = float inputs are fp32, 0 = bf16
// flags[1]: 1 = edge_index is int64, 0 = int32
__global__ void k_detect(const void* h, const void* ei, int* flags) {
    __shared__ int wild, zeros;
    if (threadIdx.x == 0) { wild = 0; zeros = 0; }
    __syncthreads();
    int t = threadIdx.x;
    const unsigned short* hb = (const unsigned short*)h;
    int lw = 0;
    for (int i = t; i < 4096; i += 256) {
        unsigned short u = hb[i];
        int e = (u >> 7) & 0xFF;
        if ((e >= 0x8F || e == 0) && (u & 0x7FFF) != 0) lw++;
    }
    atomicAdd(&wild, lw);
    const int* ii = (const int*)ei;
    int lz = 0;
    for (int i = t; i < 512; i += 256)
        if (ii[2 * i + 1] == 0) lz++;
    atomicAdd(&zeros, lz);
    __syncthreads();
    if (threadIdx.x == 0) {
        flags[0] = (wild > 256) ? 1 : 0;
        flags[1] = (zeros > 256) ? 1 : 0;
    }
}

__device__ __forceinline__ int edge_at(const void* ei, int i64, long long idx) {
    return i64 ? (int)((const long long*)ei)[idx] : ((const int*)ei)[idx];
}

__device__ __forceinline__ float flt_at(const void* p, int fp32, size_t idx) {
    return fp32 ? ((const float*)p)[idx] : (float)((const __hip_bfloat16*)p)[idx];
}

// convert the 6 small float arrays + zero counts in one launch (12 blocks)
__global__ void k_cvt_small(const void* bemb, const void* bs, const void* gam,
                            const void* bet, const void* Wm, const void* bm,
                            float* bemb_f, float* bs_f, float* gam_f, float* bet_f,
                            float* Wm_f, float* bm_f, int* counts, const int* flags) {
    int i = blockIdx.x * 256 + threadIdx.x;
    for (int j = i; j < 12500; j += 3072)
        ((int4*)counts)[j] = make_int4(0, 0, 0, 0);
    int fp32 = flags[0];
    const void* src; float* dst; int off;
    if (i < 128)       { src = bemb; dst = bemb_f; off = i; }
    else if (i < 640)  { src = bs;   dst = bs_f;   off = i - 128; }
    else if (i < 1152) { src = gam;  dst = gam_f;  off = i - 640; }
    else if (i < 1664) { src = bet;  dst = bet_f;  off = i - 1152; }
    else if (i < 2944) { src = Wm;   dst = Wm_f;   off = i - 1664; }
    else if (i < 2954) { src = bm;   dst = bm_f;   off = i - 2944; }
    else return;
    dst[off] = flt_at(src, fp32, off);
}

// ---------------- graph preprocessing ----------------
// XCD-range swizzle: block's dst-range = blockIdx&7 (matches round-robin XCD dispatch).

__global__ void k_count_edges(const void* ei, int* counts, const int* flags) {
    int rlo = (blockIdx.x & 7) * 6250, rhi = rlo + 6250;
    int i64 = flags[1];
    for (int c = (int)(blockIdx.x >> 3); c < 3125; c += 391) {
        int e = c * 256 + threadIdx.x;
        if (e < EE) {
            int d = edge_at(ei, i64, (long long)EE + e);
            if (d >= rlo && d < rhi) atomicAdd(&counts[d], 1);
        }
    }
}

// exclusive scan of (counts+1) -> offsets
__global__ void k_scan1(const int* counts, int* offsets, int* bsums) {
    __shared__ int sc[256];
    int tid = threadIdx.x;
    int base = blockIdx.x * 1024 + tid * 4;
    int4 c = {0, 0, 0, 0};
    int4 d = {0, 0, 0, 0};
    if (base + 3 < NN) {
        c = *(const int4*)(counts + base);
        d.x = c.x + 1; d.y = c.y + 1; d.z = c.z + 1; d.w = c.w + 1;
    } else {
        if (base + 0 < NN) d.x = counts[base] + 1;
        if (base + 1 < NN) d.y = counts[base + 1] + 1;
        if (base + 2 < NN) d.z = counts[base + 2] + 1;
        if (base + 3 < NN) d.w = counts[base + 3] + 1;
    }
    int s = d.x + d.y + d.z + d.w;
    sc[tid] = s;
    __syncthreads();
    for (int off = 1; off < 256; off <<= 1) {
        int v = (tid >= off) ? sc[tid - off] : 0;
        __syncthreads();
        sc[tid] += v;
        __syncthreads();
    }
    int excl = sc[tid] - s;
    if (base < NN) {
        int4 o;
        o.x = excl; o.y = excl + d.x; o.z = o.y + d.y; o.w = o.z + d.z;
        *(int4*)(offsets + base) = o;
    }
    if (tid == 255) bsums[blockIdx.x] = sc[255];
}

__global__ void k_scan2(int* bsums, int nb) {
    __shared__ int sc[64];
    int tid = threadIdx.x;
    int v = (tid < nb) ? bsums[tid] : 0;
    sc[tid] = v;
    __syncthreads();
    for (int off = 1; off < 64; off <<= 1) {
        int u = (tid >= off) ? sc[tid - off] : 0;
        __syncthreads();
        sc[tid] += u;
        __syncthreads();
    }
    if (tid < nb) bsums[tid] = sc[tid] - v;
}

// finalize offsets + zero cursor + compute dinv + place self-loops
__global__ void k_scan3(int* offsets, const int* bsums, const int* counts,
                        int* cursor, float* dinv, int* csr) {
    int base = blockIdx.x * 1024 + threadIdx.x * 4;
    if (base >= NN) return;
    int add = bsums[blockIdx.x];
    int4 o = *(int4*)(offsets + base);
    o.x += add; o.y += add; o.z += add; o.w += add;
    *(int4*)(offsets + base) = o;
    int ov[4] = {o.x, o.y, o.z, o.w};
#pragma unroll
    for (int t = 0; t < 4; ++t) {
        int i = base + t;
        if (i < NN) {
            int c = counts[i];
            cursor[i] = 0;
            dinv[i] = rsqrtf((float)(c + 1));
            csr[ov[t] + c] = i;  // self-loop in last slot of segment
        }
    }
}

__global__ void k_fill_edges(const void* ei, const int* offsets, int* cursor,
                             int* csr, const int* flags) {
    int rlo = (blockIdx.x & 7) * 6250, rhi = rlo + 6250;
    int i64 = flags[1];
    for (int c = (int)(blockIdx.x >> 3); c < 3125; c += 391) {
        int e = c * 256 + threadIdx.x;
        if (e < EE) {
            int d = edge_at(ei, i64, (long long)EE + e);
            if (d >= rlo && d < rhi) {
                int s = edge_at(ei, i64, e);
                if ((unsigned)s < NN) {
                    int pos = offsets[d] + atomicAdd(&cursor[d], 1);
                    csr[pos] = s;
                }
            }
        }
    }
}

// ---------------- weight packing into MFMA B-fragment order (hi/lo planes) ----------------
__global__ void k_pack(const void* Wemb, const void* Ws, __bf16* Bhi, __bf16* Blo,
                       const int* flags) {
    int idx = blockIdx.x * 256 + threadIdx.x;
    if (idx >= 5 * 16384) return;
    int m = idx >> 14, r = idx & 16383;
    int kt = r >> 12, nt = (r >> 9) & 7, lane = (r >> 3) & 63, j = r & 7;
    int k = kt * 32 + (lane >> 4) * 8 + j;
    int n = nt * 16 + (lane & 15);
    int fp32 = flags[0];
    float w;
    if (m == 0) w = flt_at(Wemb, fp32, (size_t)k * 128 + n);
    else        w = flt_at(Ws, fp32, (size_t)(m - 1) * 16384 + (size_t)k * 128 + n);
    __bf16 hi = (__bf16)w;
    Bhi[idx] = hi;
    Blo[idx] = (__bf16)(w - (float)hi);
}

// ---------------- BN affine helper: S,T from raw sums ----------------
__device__ __forceinline__ void bn_affine(float sm, float sq, float g, float be,
                                          float& S, float& T) {
    float mu = sm * (1.f / NN);
    float var = fmaxf(sq * (1.f / NN) - mu * mu, 0.f);
    S = rsqrtf(var + BN_EPS) * g;
    T = be - mu * S;
}

// sum 8 replicas of column-quad cb from stats8
__device__ __forceinline__ void sum_reps(const float* ST, int cb, float4& sm, float4& sq) {
    sm = make_float4(0.f, 0.f, 0.f, 0.f);
    sq = make_float4(0.f, 0.f, 0.f, 0.f);
#pragma unroll
    for (int rr = 0; rr < 8; ++rr) {
        float4 a = *(const float4*)(ST + rr * 256 + cb);
        float4 b = *(const float4*)(ST + rr * 256 + 128 + cb);
        sm.x += a.x; sm.y += a.y; sm.z += a.z; sm.w += a.w;
        sq.x += b.x; sq.y += b.y; sq.z += b.z; sq.w += b.w;
    }
}

// ---------------- MFMA GEMM ----------------
// mode 0: A = raw network input (fp32/bf16 per flags[0]); bias in epilogue; fp32 C out.
// mode 1: A = fp32 hbuf; bf16 Cb out (row layout xb[node][64 uint]).
// mode 2: A-row = hbuf + relu(abuf*S + T); writes h' to Hout; bf16 Cb out.
__global__ __launch_bounds__(256) void k_gemm_mfma(const void* __restrict__ Araw,
                                                   const float* __restrict__ Aagg,
                                                   const float* __restrict__ ST,
                                                   const float* __restrict__ gamma,
                                                   const float* __restrict__ beta,
                                                   const __bf16* __restrict__ Bhi,
                                                   const __bf16* __restrict__ Blo,
                                                   const float* __restrict__ bias,
                                                   float* __restrict__ C,
                                                   unsigned short* __restrict__ Cb,
                                                   float* __restrict__ Hout,
                                                   int M, int mode, const int* flags) {
    // a_hi/a_lo overlaid with the epilogue C-scratch (dead after MFMA loop)
    __shared__ __align__(16) char smem[2 * 64 * 136 * 2];  // 34816 B
    __bf16 (*a_hi)[136] = (__bf16(*)[136])smem;
    __bf16 (*a_lo)[136] = (__bf16(*)[136])(smem + 64 * 136 * 2);
    float (*Cs)[132] = (float(*)[132])smem;                 // 33792 B, fits
    int tid = threadIdx.x;
    int r0 = blockIdx.x * 64;
    int cq = tid & 31;
    int rb = tid >> 5;
    int cb = cq * 4;
    float4 S4, T4;
    if (mode == 2) {
        float4 sm, sq;
        sum_reps(ST, cb, sm, sq);
        float4 g  = *(const float4*)(gamma + cb);
        float4 be = *(const float4*)(beta + cb);
        bn_affine(sm.x, sq.x, g.x, be.x, S4.x, T4.x);
        bn_affine(sm.y, sq.y, g.y, be.y, S4.y, T4.y);
        bn_affine(sm.z, sq.z, g.z, be.z, S4.z, T4.z);
        bn_affine(sm.w, sq.w, g.w, be.w, S4.w, T4.w);
    }
    int afp32 = (mode == 0) ? flags[0] : 1;
#pragma unroll
    for (int p = 0; p < 8; ++p) {
        int r = rb + p * 8;
        int gr = r0 + r;
        float f[4] = {0.f, 0.f, 0.f, 0.f};
        if (gr < M) {
            if (mode == 0) {
                if (afp32) {
                    float4 v = ((const float4*)Araw)[(size_t)gr * 32 + cq];
                    f[0] = v.x; f[1] = v.y; f[2] = v.z; f[3] = v.w;
                } else {
                    const __hip_bfloat16* ab = (const __hip_bfloat16*)Araw + (size_t)gr * 128 + cb;
#pragma unroll
                    for (int t = 0; t < 4; ++t) f[t] = (float)ab[t];
                }
            } else {
                float4 v = *(const float4*)((const float*)Araw + (size_t)gr * 128 + cb);
                if (mode == 2) {
                    float4 a = *(const float4*)(Aagg + (size_t)gr * 128 + cb);
                    v.x += fmaxf(fmaf(a.x, S4.x, T4.x), 0.f);
                    v.y += fmaxf(fmaf(a.y, S4.y, T4.y), 0.f);
                    v.z += fmaxf(fmaf(a.z, S4.z, T4.z), 0.f);
                    v.w += fmaxf(fmaf(a.w, S4.w, T4.w), 0.f);
                    *(float4*)(Hout + (size_t)gr * 128 + cb) = v;
                }
                f[0] = v.x; f[1] = v.y; f[2] = v.z; f[3] = v.w;
            }
        }
        union { __bf16 b[4]; ushort4 u; } ph, pl;
#pragma unroll
        for (int t = 0; t < 4; ++t) {
            __bf16 hi = (__bf16)f[t];
            ph.b[t] = hi;
            pl.b[t] = (__bf16)(f[t] - (float)hi);
        }
        *(ushort4*)&a_hi[r][cb] = ph.u;
        *(ushort4*)&a_lo[r][cb] = pl.u;
    }
    __syncthreads();
    int lane = tid & 63, wave = tid >> 6;
    int quad = lane >> 4, l15 = lane & 15;
    int rw = wave * 16;
    f32x4 acc[8];
#pragma unroll
    for (int nt = 0; nt < 8; ++nt) acc[nt] = (f32x4){0.f, 0.f, 0.f, 0.f};
#pragma unroll
    for (int kt = 0; kt < 4; ++kt) {
        int k0 = kt * 32 + quad * 8;
        bf16x8 ah = *(const bf16x8*)&a_hi[rw + l15][k0];
        bf16x8 al = *(const bf16x8*)&a_lo[rw + l15][k0];
#pragma unroll
        for (int nt = 0; nt < 8; ++nt) {
            size_t boff = (((size_t)(kt * 8 + nt) * 64 + lane) * 8);
            bf16x8 bh = *(const bf16x8*)(Bhi + boff);
            bf16x8 bl = *(const bf16x8*)(Blo + boff);
            acc[nt] = __builtin_amdgcn_mfma_f32_16x16x32_bf16(ah, bh, acc[nt], 0, 0, 0);
            acc[nt] = __builtin_amdgcn_mfma_f32_16x16x32_bf16(al, bh, acc[nt], 0, 0, 0);
            acc[nt] = __builtin_amdgcn_mfma_f32_16x16x32_bf16(ah, bl, acc[nt], 0, 0, 0);
        }
    }
    // epilogue: stage C tile in LDS, then coalesced wide stores
    __syncthreads();
#pragma unroll
    for (int nt = 0; nt < 8; ++nt) {
        int col = nt * 16 + l15;
#pragma unroll
        for (int reg = 0; reg < 4; ++reg)
            Cs[rw + quad * 4 + reg][col] = acc[nt][reg];
    }
    __syncthreads();
#pragma unroll
    for (int p = 0; p < 4; ++p) {
        int row = (tid >> 4) + p * 16;
        int gr = r0 + row;
        if (gr >= M) continue;
        int colc = (tid & 15) * 8;
        float v[8];
        *(float4*)&v[0] = *(const float4*)&Cs[row][colc];
        *(float4*)&v[4] = *(const float4*)&Cs[row][colc + 4];
        if (bias) {
            float4 b0 = *(const float4*)(bias + colc);
            float4 b1 = *(const float4*)(bias + colc + 4);
            v[0] += b0.x; v[1] += b0.y; v[2] += b0.z; v[3] += b0.w;
            v[4] += b1.x; v[5] += b1.y; v[6] += b1.z; v[7] += b1.w;
        }
        if (Cb) {
            union { unsigned short us[8]; uint4 u4; } pk;
#pragma unroll
            for (int t = 0; t < 8; ++t)
                pk.us[t] = __bfloat16_as_ushort(__float2bfloat16(v[t]));
            *(uint4*)(Cb + (size_t)gr * 128 + colc) = pk.u4;
        } else {
            float* cr = C + (size_t)gr * 128 + colc;
            *(float4*)cr = *(float4*)&v[0];
            *(float4*)(cr + 4) = *(float4*)&v[4];
        }
    }
}

// ---------------- aggregation + stats8 zeroing ----------------
// Row layout xb[node][64 uint]. 16B/lane gather: lane quarter q handles edge j+q;
// one load inst covers 4 edges; 2 loads in flight; single-load tail for <=4 edges.
__global__ __launch_bounds__(256) void k_agg(const unsigned int* __restrict__ xb,
                                             const int* __restrict__ csr,
                                             const int* __restrict__ offsets,
                                             const int* __restrict__ counts,
                                             const float* __restrict__ dinv,
                                             const float* __restrict__ bias,
                                             float* __restrict__ out,
                                             float* __restrict__ stats8) {
    if (blockIdx.x < 8) stats8[blockIdx.x * 256 + threadIdx.x] = 0.f;  // zero replicas
    int node = blockIdx.x * 4 + (threadIdx.x >> 6);
    int lane = threadIdx.x & 63;
    int l15 = lane & 15;
    int quarter = lane >> 4;
    int start = offsets[node];
    int cnt = counts[node] + 1;  // + self-loop
    float dn = dinv[node];
    float accA[8] = {0.f, 0.f, 0.f, 0.f, 0.f, 0.f, 0.f, 0.f};
    float accB[8] = {0.f, 0.f, 0.f, 0.f, 0.f, 0.f, 0.f, 0.f};
    for (int base = 0; base < cnt; base += 64) {
        int sidx = 0;
        float wl = 0.f;
        if (base + lane < cnt) {
            sidx = csr[start + base + lane];
            wl = dinv[sidx] * dn;  // wl = 0 for slots beyond cnt
        }
        int m = min(64, cnt - base);
        int j = 0;
        for (; j + 4 < m; j += 8) {        // >=5 edges remain: 2 loads (8 edges)
            int e0 = j + quarter;
            int e1 = j + 4 + quarter;
            int s0 = __shfl(sidx, e0);
            float w0 = __shfl(wl, e0);
            int s1 = __shfl(sidx, e1);
            float w1 = __shfl(wl, e1);
            uint4 u0 = *((const uint4*)(xb + (size_t)s0 * 64) + l15);
            uint4 u1 = *((const uint4*)(xb + (size_t)s1 * 64) + l15);
            accA[0] = fmaf(bf_lo(u0.x), w0, accA[0]);
            accA[1] = fmaf(bf_hi(u0.x), w0, accA[1]);
            accA[2] = fmaf(bf_lo(u0.y), w0, accA[2]);
            accA[3] = fmaf(bf_hi(u0.y), w0, accA[3]);
            accA[4] = fmaf(bf_lo(u0.z), w0, accA[4]);
            accA[5] = fmaf(bf_hi(u0.z), w0, accA[5]);
            accA[6] = fmaf(bf_lo(u0.w), w0, accA[6]);
            accA[7] = fmaf(bf_hi(u0.w), w0, accA[7]);
            accB[0] = fmaf(bf_lo(u1.x), w1, accB[0]);
            accB[1] = fmaf(bf_hi(u1.x), w1, accB[1]);
            accB[2] = fmaf(bf_lo(u1.y), w1, accB[2]);
            accB[3] = fmaf(bf_hi(u1.y), w1, accB[3]);
            accB[4] = fmaf(bf_lo(u1.z), w1, accB[4]);
            accB[5] = fmaf(bf_hi(u1.z), w1, accB[5]);
            accB[6] = fmaf(bf_lo(u1.w), w1, accB[6]);
            accB[7] = fmaf(bf_hi(u1.w), w1, accB[7]);
        }
        if (j < m) {                        // <=4 edges remain: 1 load
            int e0 = j + quarter;
            int s0 = __shfl(sidx, e0);
            float w0 = __shfl(wl, e0);
            uint4 u0 = *((const uint4*)(xb + (size_t)s0 * 64) + l15);
            accA[0] = fmaf(bf_lo(u0.x), w0, accA[0]);
            accA[1] = fmaf(bf_hi(u0.x), w0, accA[1]);
            accA[2] = fmaf(bf_lo(u0.y), w0, accA[2]);
            accA[3] = fmaf(bf_hi(u0.y), w0, accA[3]);
            accA[4] = fmaf(bf_lo(u0.z), w0, accA[4]);
            accA[5] = fmaf(bf_hi(u0.z), w0, accA[5]);
            accA[6] = fmaf(bf_lo(u0.w), w0, accA[6]);
            accA[7] = fmaf(bf_hi(u0.w), w0, accA[7]);
        }
    }
#pragma unroll
    for (int k = 0; k < 8; ++k) {
        float a = accA[k] + accB[k];
        a += __shfl_xor(a, 16);
        a += __shfl_xor(a, 32);
        accA[k] = a;
    }
    if (quarter == 0) {
        int col = l15 * 8;
        float4 o0, o1;
        o0.x = accA[0] + bias[col + 0];
        o0.y = accA[1] + bias[col + 1];
        o0.z = accA[2] + bias[col + 2];
        o0.w = accA[3] + bias[col + 3];
        o1.x = accA[4] + bias[col + 4];
        o1.y = accA[5] + bias[col + 5];
        o1.z = accA[6] + bias[col + 6];
        o1.w = accA[7] + bias[col + 7];
        float* orow = out + (size_t)node * 128 + col;
        *(float4*)orow = o0;
        *(float4*)(orow + 4) = o1;
    }
}

// ---------------- batchnorm partials: grid-stride, 8-replica atomics ----------------
__global__ __launch_bounds__(256) void k_bnred(const float* __restrict__ agg,
                                               float* __restrict__ stats8) {
    int tid = threadIdx.x;
    int rt = tid >> 5, cq = tid & 31;   // 8 row-threads x 32 col-quads
    float4 s = {0.f, 0.f, 0.f, 0.f}, ss = {0.f, 0.f, 0.f, 0.f};
    for (int chunk = blockIdx.x; chunk < NCHUNK; chunk += gridDim.x) {
        int r0 = chunk * 64;
#pragma unroll
        for (int p = 0; p < 8; ++p) {
            int row = r0 + p * 8 + rt;
            if (row < NN) {
                float4 v = *(const float4*)(agg + (size_t)row * 128 + cq * 4);
                s.x += v.x; s.y += v.y; s.z += v.z; s.w += v.w;
                ss.x = fmaf(v.x, v.x, ss.x);
                ss.y = fmaf(v.y, v.y, ss.y);
                ss.z = fmaf(v.z, v.z, ss.z);
                ss.w = fmaf(v.w, v.w, ss.w);
            }
        }
    }
    __shared__ float4 lsum[8][33], lssq[8][33];
    lsum[rt][cq] = s;
    lssq[rt][cq] = ss;
    __syncthreads();
    if (tid < 32) {
        float4 ts = lsum[0][tid], tq = lssq[0][tid];
#pragma unroll
        for (int r = 1; r < 8; ++r) {
            float4 a = lsum[r][tid], b = lssq[r][tid];
            ts.x += a.x; ts.y += a.y; ts.z += a.z; ts.w += a.w;
            tq.x += b.x; tq.y += b.y; tq.z += b.z; tq.w += b.w;
        }
        float* st = stats8 + (blockIdx.x & 7) * 256;
        atomicAdd(&st[tid * 4 + 0], ts.x);
        atomicAdd(&st[tid * 4 + 1], ts.y);
        atomicAdd(&st[tid * 4 + 2], ts.z);
        atomicAdd(&st[tid * 4 + 3], ts.w);
        atomicAdd(&st[128 + tid * 4 + 0], tq.x);
        atomicAdd(&st[128 + tid * 4 + 1], tq.y);
        atomicAdd(&st[128 + tid * 4 + 2], tq.z);
        atomicAdd(&st[128 + tid * 4 + 3], tq.w);
    }
}

// ---------------- fused final BN + MLP: out[N x 10] ----------------
__global__ __launch_bounds__(256) void k_mlp_fused(const float* __restrict__ h,
                                                   const float* __restrict__ agg,
                                                   const float* __restrict__ ST,
                                                   const float* __restrict__ gamma,
                                                   const float* __restrict__ beta,
                                                   const float* __restrict__ Wm,
                                                   const float* __restrict__ bm,
                                                   void* __restrict__ out,
                                                   const int* __restrict__ flags) {
    __shared__ float Wt[10][132];
    int tid = threadIdx.x;
    for (int i = tid; i < 1280; i += 256) {
        int cls = i >> 7, k = i & 127;
        Wt[cls][k] = Wm[k * 10 + cls];
    }
    __syncthreads();
    int wave = tid >> 6, lane = tid & 63;
    int nl = lane >> 4, c = lane & 15;
    int node = blockIdx.x * 16 + wave * 4 + nl;
    size_t rowo = (size_t)node * 128 + c * 8;
    float4 h0 = *(const float4*)(h + rowo);
    float4 h1 = *(const float4*)(h + rowo + 4);
    float4 a0 = *(const float4*)(agg + rowo);
    float4 a1 = *(const float4*)(agg + rowo + 4);
    float S[8], T[8];
#pragma unroll
    for (int q = 0; q < 2; ++q) {
        float4 sm, sq;
        sum_reps(ST, c * 8 + q * 4, sm, sq);
        float4 g  = *(const float4*)(gamma + c * 8 + q * 4);
        float4 be = *(const float4*)(beta + c * 8 + q * 4);
        bn_affine(sm.x, sq.x, g.x, be.x, S[q * 4 + 0], T[q * 4 + 0]);
        bn_affine(sm.y, sq.y, g.y, be.y, S[q * 4 + 1], T[q * 4 + 1]);
        bn_affine(sm.z, sq.z, g.z, be.z, S[q * 4 + 2], T[q * 4 + 2]);
        bn_affine(sm.w, sq.w, g.w, be.w, S[q * 4 + 3], T[q * 4 + 3]);
    }
    float hv[8];
    hv[0] = h0.x + fmaxf(fmaf(a0.x, S[0], T[0]), 0.f);
    hv[1] = h0.y + fmaxf(fmaf(a0.y, S[1], T[1]), 0.f);
    hv[2] = h0.z + fmaxf(fmaf(a0.z, S[2], T[2]), 0.f);
    hv[3] = h0.w + fmaxf(fmaf(a0.w, S[3], T[3]), 0.f);
    hv[4] = h1.x + fmaxf(fmaf(a1.x, S[4], T[4]), 0.f);
    hv[5] = h1.y + fmaxf(fmaf(a1.y, S[5], T[5]), 0.f);
    hv[6] = h1.z + fmaxf(fmaf(a1.z, S[6], T[6]), 0.f);
    hv[7] = h1.w + fmaxf(fmaf(a1.w, S[7], T[7]), 0.f);
    float p[10];
#pragma unroll
    for (int cls = 0; cls < 10; ++cls) {
        float4 w0 = *(const float4*)&Wt[cls][c * 8];
        float4 w1 = *(const float4*)&Wt[cls][c * 8 + 4];
        float sacc = fmaf(hv[0], w0.x, fmaf(hv[1], w0.y, fmaf(hv[2], w0.z, hv[3] * w0.w)));
        sacc = fmaf(hv[4], w1.x, fmaf(hv[5], w1.y, fmaf(hv[6], w1.z, fmaf(hv[7], w1.w, sacc))));
        p[cls] = sacc;
    }
#pragma unroll
    for (int m = 1; m < 16; m <<= 1)
#pragma unroll
        for (int cls = 0; cls < 10; ++cls)
            p[cls] += __shfl_xor(p[cls], m);
    if (c == 0) {
        if (flags[0]) {
            float* o = (float*)out;
            for (int cls = 0; cls < 10; ++cls) o[node * 10 + cls] = p[cls] + bm[cls];
        } else {
            __hip_bfloat16* o = (__hip_bfloat16*)out;
            for (int cls = 0; cls < 10; ++cls)
                o[node * 10 + cls] = __float2bfloat16(p[cls] + bm[cls]);
        }
    }
}

// ---------------- orchestration ----------------

extern "C" void kernel_launch(void* const* d_in, const int* in_sizes, int n_in,
                              void* d_out, int out_size, void* d_ws, size_t ws_size,
                              hipStream_t stream) {
    const void* h_in = d_in[0];
    const void* ei   = d_in[1];
    const void* Wemb = d_in[3];
    const void* bemb = d_in[4];
    const void* Ws   = d_in[5];
    const void* bs   = d_in[6];
    const void* gam  = d_in[7];
    const void* bet  = d_in[8];
    const void* Wm   = d_in[9];
    const void* bm   = d_in[10];

    char* ws = (char*)d_ws;
    size_t off = 0;
    auto alloc = [&](size_t bytes) -> void* {
        void* p = ws + off;
        off = (off + bytes + 255) & ~(size_t)255;
        return p;
    };
    float* hbuf    = (float*)alloc((size_t)NN * 128 * 4);
    float* abuf    = (float*)alloc((size_t)NN * 128 * 4);
    unsigned int* xb = (unsigned int*)alloc((size_t)NN * 64 * 4);   // bf16 x, 256 B/row
    int* counts    = (int*)alloc((size_t)(NN + 1024) * 4);
    int* offsets   = (int*)alloc((size_t)(NN + 1024) * 4);
    int* cursor    = (int*)alloc((size_t)NN * 4);
    int* bsums     = (int*)alloc(64 * 4);
    float* dinv    = (float*)alloc((size_t)NN * 4);
    float* stats8  = (float*)alloc((size_t)8 * 256 * 4);
    int* csr       = (int*)alloc((size_t)(EE + NN + 64) * 4);
    int* flags     = (int*)alloc(64);
    float* bemb_f  = (float*)alloc(128 * 4);
    float* bs_f    = (float*)alloc(512 * 4);
    float* gam_f   = (float*)alloc(512 * 4);
    float* bet_f   = (float*)alloc(512 * 4);
    float* Wm_f    = (float*)alloc(1280 * 4);
    float* bm_f    = (float*)alloc(16 * 4);
    __bf16* Bhi    = (__bf16*)alloc((size_t)5 * 16384 * 2);
    __bf16* Blo    = (__bf16*)alloc((size_t)5 * 16384 * 2);

    k_detect<<<1, 256, 0, stream>>>(h_in, ei, flags);
    k_cvt_small<<<12, 256, 0, stream>>>(bemb, bs, gam, bet, Wm, bm,
                                        bemb_f, bs_f, gam_f, bet_f, Wm_f, bm_f,
                                        counts, flags);
    k_pack<<<(5 * 16384 + 255) / 256, 256, 0, stream>>>(Wemb, Ws, Bhi, Blo, flags);

    k_count_edges<<<3128, 256, 0, stream>>>(ei, counts, flags);
    int nb = (NN + 1023) / 1024;  // 49
    k_scan1<<<nb, 256, 0, stream>>>(counts, offsets, bsums);
    k_scan2<<<1, 64, 0, stream>>>(bsums, nb);
    k_scan3<<<nb, 256, 0, stream>>>(offsets, bsums, counts, cursor, dinv, csr);
    k_fill_edges<<<3128, 256, 0, stream>>>(ei, offsets, cursor, csr, flags);

    int gblocks = (NN + 63) / 64;  // 782
    // embedding: hbuf = input @ W_emb + b_emb  (fp32 out, raw input staged directly)
    k_gemm_mfma<<<gblocks, 256, 0, stream>>>(h_in, nullptr, nullptr, nullptr, nullptr,
                                             Bhi, Blo, bemb_f, hbuf, nullptr, nullptr,
                                             NN, 0, flags);

    for (int l = 0; l < NL; ++l) {
        if (l == 0) {
            k_gemm_mfma<<<gblocks, 256, 0, stream>>>(hbuf, nullptr, nullptr, nullptr, nullptr,
                                                     Bhi + (size_t)1 * 16384, Blo + (size_t)1 * 16384,
                                                     nullptr, nullptr, (unsigned short*)xb,
                                                     nullptr, NN, 1, flags);
        } else {
            // fused: h = h + relu(BN_{l-1}(abuf)), then x = h @ W_l
            k_gemm_mfma<<<gblocks, 256, 0, stream>>>(hbuf, abuf, stats8,
                                                     gam_f + (l - 1) * 128, bet_f + (l - 1) * 128,
                                                     Bhi + (size_t)(1 + l) * 16384,
                                                     Blo + (size_t)(1 + l) * 16384,
                                                     nullptr, nullptr, (unsigned short*)xb,
                                                     hbuf, NN, 2, flags);
        }
        k_agg<<<NN / 4, 256, 0, stream>>>(xb, csr, offsets, counts, dinv,
                                          bs_f + l * 128, abuf, stats8);
        k_bnred<<<196, 256, 0, stream>>>(abuf, stats8);
    }
    // final: h4 = h3 + relu(BN_3(abuf)); out = h4 @ W_mlp + b_mlp
    k_mlp_fused<<<NN / 16, 256, 0, stream>>>(hbuf, abuf, stats8,
                                             gam_f + 3 * 128, bet_f + 3 * 128,
                                             Wm_f, bm_f, d_out, flags);
}